// Round 15
// baseline (116.340 us; speedup 1.0000x reference)
//
#include <hip/hip_runtime.h>
#include <math.h>

#define NCOL 32
#define DDIM 512
#define NPAIR 16
#define CATS 10
#define ROW_STRIDE (NCOL * DDIM)   /* 16384 floats between consecutive b rows */
#define SLAB_FLOATS 4096           /* 4 pairs x 1024 floats = 16 KiB per row  */

// v += dpp_permuted(v). old=0 / bound_ctrl=false: masked-off rows contribute 0.
template <int CTRL, int ROW_MASK>
__device__ __forceinline__ float dpp_add(float v) {
    int t = __builtin_amdgcn_update_dpp(0, __float_as_int(v), CTRL, ROW_MASK, 0xf, false);
    return v + __int_as_float(t);
}
// pure DPP move: returns permuted value (0 in masked-off rows).
template <int CTRL, int ROW_MASK>
__device__ __forceinline__ float dpp_mov(float v) {
    int t = __builtin_amdgcn_update_dpp(0, __float_as_int(v), CTRL, ROW_MASK, 0xf, false);
    return __int_as_float(t);
}

// After this: lane31 = sum(lanes 0..31), lane63 = sum(lanes 32..63). VALU only.
__device__ __forceinline__ float wave_reduce_halves(float v) {
    v = dpp_add<0x111, 0xf>(v);  // row_shr:1
    v = dpp_add<0x112, 0xf>(v);  // row_shr:2
    v = dpp_add<0x114, 0xf>(v);  // row_shr:4
    v = dpp_add<0x118, 0xf>(v);  // row_shr:8  -> lane15 of each row16 = row sum
    v = dpp_add<0x142, 0xa>(v);  // row_bcast:15 -> lane31, lane63 hold half-sums
    return v;
}
// Full 64-lane sum, valid in lane 63.
__device__ __forceinline__ float wave_reduce_full(float v) {
    v = wave_reduce_halves(v);
    v = dpp_add<0x143, 0xc>(v);  // row_bcast:31 into rows 2,3 -> lane63 = total
    return v;
}

// R6's proven 6.6TB/s structure (block-cooperative reg-bounce slab, double-
// buffered LDS, one __syncthreads per row) on a persistent 768-block grid
// (exactly 3 blocks/CU resident -> no scheduling rounds, R6's only loss).
__global__ __launch_bounds__(256, 3) void fused_pairs_persist(
    const float* __restrict__ x,
    const float* __restrict__ Wn,
    const float* __restrict__ bn,
    const float* __restrict__ Wc,
    const float* __restrict__ bc,
    float* __restrict__ out)
{
    __shared__ __align__(16) float buf[2][SLAB_FLOATS];   // 32 KiB
    const int tid   = threadIdx.x;
    const int lane  = tid & 63;
    const int wslot = tid >> 6;
    const int q     = __builtin_amdgcn_readfirstlane(blockIdx.x & 3);  // quad
    const int band  = __builtin_amdgcn_readfirstlane(blockIdx.x >> 2); // 0..191
    // contiguous band: bands 0..127 -> 43 rows, 128..191 -> 42 rows
    const int start = __builtin_amdgcn_readfirstlane(
        (band < 128) ? band * 43 : 5504 + (band - 128) * 42);
    const int n     = __builtin_amdgcn_readfirstlane((band < 128) ? 43 : 42);
    const int p     = __builtin_amdgcn_readfirstlane(q * 4 + wslot); // pair

    // ---- numeric weights (per-lane slice of Wn[p]) — identical to R6
    float w[8];
    {
        float4 wa = *(const float4*)(Wn + p * DDIM + lane * 4);
        float4 wb = *(const float4*)(Wn + p * DDIM + 256 + lane * 4);
        w[0]=wa.x; w[1]=wa.y; w[2]=wa.z; w[3]=wa.w;
        w[4]=wb.x; w[5]=wb.y; w[6]=wb.z; w[7]=wb.w;
    }
    const float bias = __int_as_float(
        __builtin_amdgcn_readfirstlane(__float_as_int(bn[p])));

    // ---- categorical weights: wc[dd*10+c] low half, wc[40+dd*10+c] high half
    float wc[80];
    {
        const float* w0 = Wc + ((size_t)p * DDIM + lane * 4) * CATS;
        const float* w1 = Wc + ((size_t)p * DDIM + 256 + lane * 4) * CATS;
        #pragma unroll
        for (int k = 0; k < 10; ++k) {
            float4 t = *(const float4*)(w0 + k * 4);
            wc[4*k] = t.x; wc[4*k+1] = t.y; wc[4*k+2] = t.z; wc[4*k+3] = t.w;
        }
        #pragma unroll
        for (int k = 0; k < 10; ++k) {
            float4 t = *(const float4*)(w1 + k * 4);
            wc[40+4*k] = t.x; wc[40+4*k+1] = t.y; wc[40+4*k+2] = t.z; wc[40+4*k+3] = t.w;
        }
    }
    double biasd[CATS];  // wave-uniform -> SGPR pairs (as in passing R6)
    #pragma unroll
    for (int c = 0; c < CATS; ++c)
        biasd[c] = (double)__int_as_float(
            __builtin_amdgcn_readfirstlane(__float_as_int(bc[p * CATS + c])));

    // slab base: row `start`, columns 8q..8q+7 (pairs 4q..4q+3), 16 KiB/row
    const float* xslab = x + (size_t)start * ROW_STRIDE + (size_t)q * SLAB_FLOATS;
    float* ob = out + (size_t)start * NCOL + 2 * p;

    // ---- prologue: stage row 0 into buf[0] (fully coalesced, 16B/thread x4)
    {
        const float* g = xslab;
        #pragma unroll
        for (int it = 0; it < 4; ++it)
            *(float4*)(&buf[0][it * 1024 + tid * 4]) =
                *(const float4*)(g + it * 1024 + tid * 4);
    }
    __syncthreads();

    for (int r = 0; r < n; ++r) {
        const int cur = r & 1;
        const int nxt = cur ^ 1;

        // issue next row's global loads early (latency hides under compute)
        float4 s0, s1, s2, s3;
        const bool have_next = (r + 1 < n);
        if (have_next) {
            const float* g = xslab + (size_t)(r + 1) * ROW_STRIDE;
            s0 = *(const float4*)(g +    0 + tid * 4);
            s1 = *(const float4*)(g + 1024 + tid * 4);
            s2 = *(const float4*)(g + 2048 + tid * 4);
            s3 = *(const float4*)(g + 3072 + tid * 4);
        }

        // this wave's pair from LDS: [E(512) | O(512)] at wslot*1024
        const float* pb = &buf[cur][wslot * 1024];
        float4 Oa = *(const float4*)(pb + 512 + 4 * lane);
        float4 Ob = *(const float4*)(pb + 512 + 256 + 4 * lane);
        float4 Ea = *(const float4*)(pb + 4 * lane);
        float4 Eb = *(const float4*)(pb + 256 + 4 * lane);

        // ---- categorical on odd col (math byte-identical to R6)
        double best = -1.0e300;
        int bi = 0;
        #pragma unroll
        for (int c = 0; c < CATS; ++c) {
            float s = Oa.x * wc[c];
            s = fmaf(Oa.y, wc[10 + c], s);
            s = fmaf(Oa.z, wc[20 + c], s);
            s = fmaf(Oa.w, wc[30 + c], s);
            s = fmaf(Ob.x, wc[40 + c], s);
            s = fmaf(Ob.y, wc[50 + c], s);
            s = fmaf(Ob.z, wc[60 + c], s);
            s = fmaf(Ob.w, wc[70 + c], s);
            s = wave_reduce_halves(s);
            float slo = dpp_mov<0x143, 0xc>(s);
            double d = (double)s + (double)slo + biasd[c];
            if (d > best) { best = d; bi = c; }
        }

        // ---- numeric on even col (math byte-identical to R6)
        float sn = Ea.x * w[0];
        sn = fmaf(Ea.y, w[1], sn);
        sn = fmaf(Ea.z, w[2], sn);
        sn = fmaf(Ea.w, w[3], sn);
        sn = fmaf(Eb.x, w[4], sn);
        sn = fmaf(Eb.y, w[5], sn);
        sn = fmaf(Eb.z, w[6], sn);
        sn = fmaf(Eb.w, w[7], sn);
        sn = wave_reduce_full(sn);

        if (lane == 63) {
            float2 o2 = make_float2(tanhf(sn + bias), (float)bi);
            *(float2*)(ob + (size_t)r * NCOL) = o2;
        }

        // write next row's slab (buf[nxt] was fully consumed at row r-1)
        if (have_next) {
            *(float4*)(&buf[nxt][   0 + tid * 4]) = s0;
            *(float4*)(&buf[nxt][1024 + tid * 4]) = s1;
            *(float4*)(&buf[nxt][2048 + tid * 4]) = s2;
            *(float4*)(&buf[nxt][3072 + tid * 4]) = s3;
        }
        __syncthreads();
    }
}

extern "C" void kernel_launch(void* const* d_in, const int* in_sizes, int n_in,
                              void* d_out, int out_size, void* d_ws, size_t ws_size,
                              hipStream_t stream) {
    const float* x  = (const float*)d_in[0];
    const float* Wn = (const float*)d_in[1];
    const float* bn = (const float*)d_in[2];
    const float* Wc = (const float*)d_in[3];
    const float* bc = (const float*)d_in[4];
    float* out = (float*)d_out;

    // 768 blocks = 192 bands x 4 quads; exactly 3 blocks/CU co-resident.
    hipLaunchKernelGGL(fused_pairs_persist, dim3(768), dim3(256), 0, stream,
                       x, Wn, bn, Wc, bc, out);
}

// Round 16
// 89.598 us; speedup vs baseline: 1.2985x; 1.2985x over previous
//
#include <hip/hip_runtime.h>
#include <math.h>

#define NCOL 32
#define DDIM 512
#define NPAIR 16
#define CATS 10
#define ROW_STRIDE (NCOL * DDIM)   /* 16384 floats between consecutive b rows */
#define NBODY 192                  /* row-stride between a block's rows       */
#define TOTROWS 8192

// v += dpp_permuted(v). old=0 / bound_ctrl=false: masked-off rows contribute 0.
template <int CTRL, int ROW_MASK>
__device__ __forceinline__ float dpp_add(float v) {
    int t = __builtin_amdgcn_update_dpp(0, __float_as_int(v), CTRL, ROW_MASK, 0xf, false);
    return v + __int_as_float(t);
}
// pure DPP move: returns permuted value (0 in masked-off rows).
template <int CTRL, int ROW_MASK>
__device__ __forceinline__ float dpp_mov(float v) {
    int t = __builtin_amdgcn_update_dpp(0, __float_as_int(v), CTRL, ROW_MASK, 0xf, false);
    return __int_as_float(t);
}

// After this: lane31 = sum(lanes 0..31), lane63 = sum(lanes 32..63). VALU only.
__device__ __forceinline__ float wave_reduce_halves(float v) {
    v = dpp_add<0x111, 0xf>(v);  // row_shr:1
    v = dpp_add<0x112, 0xf>(v);  // row_shr:2
    v = dpp_add<0x114, 0xf>(v);  // row_shr:4
    v = dpp_add<0x118, 0xf>(v);  // row_shr:8  -> lane15 of each row16 = row sum
    v = dpp_add<0x142, 0xa>(v);  // row_bcast:15 -> lane31, lane63 hold half-sums
    return v;
}
// Full 64-lane sum, valid in lane 63.
__device__ __forceinline__ float wave_reduce_full(float v) {
    v = wave_reduce_halves(v);
    v = dpp_add<0x143, 0xc>(v);  // row_bcast:31 into rows 2,3 -> lane63 = total
    return v;
}

// counted vmcnt wait; "memory" clobber orders surrounding memory ops
#define WAITVM(n)  asm volatile("s_waitcnt vmcnt(" #n ")" ::: "memory")
// fence: ds_reads above must have landed before ops below may issue
#define WAITLGKM() asm volatile("s_waitcnt lgkmcnt(0)" ::: "memory")

// stage one pair-row (4 KiB) HBM -> LDS slot, NON-TEMPORAL (CPol NT bit = 2):
// x is streamed once; evict-first policy stops dead lines from churning L2.
#define ISSUE(row, slot) do {                                                  \
    const float* _g = x + (size_t)(row) * ROW_STRIDE + xcoloff;                \
    float* _l = &slab[wslot][slot][0];                                         \
    _Pragma("unroll")                                                          \
    for (int _k = 0; _k < 4; ++_k)                                             \
        __builtin_amdgcn_global_load_lds(                                      \
            (const __attribute__((address_space(1))) unsigned int*)            \
                (_g + _k * 256 + lane * 4),                                    \
            (__attribute__((address_space(3))) unsigned int*)(_l + _k * 256),  \
            16, 0, 2 /* NT */);                                                \
} while (0)

// one pipeline step: wait row r, pull frags LDS->regs, REFILL the slot early
// (issue before the ~600cy compute), then compute and store. Math is
// byte-identical to all passing rounds.
#define STEP(WAITSTMT, ISSUESTMT) do {                                         \
    WAITSTMT;                                                                  \
    const float* pb = &slab[wslot][s][0];                                      \
    float4 Ea = *(const float4*)(pb +   0 + 4 * lane);                         \
    float4 Eb = *(const float4*)(pb + 256 + 4 * lane);                         \
    float4 Oa = *(const float4*)(pb + 512 + 4 * lane);                         \
    float4 Ob = *(const float4*)(pb + 768 + 4 * lane);                         \
    WAITLGKM();                                                                \
    ISSUESTMT;                                                                 \
    double best = -1.0e300;                                                    \
    int bi = 0;                                                                \
    _Pragma("unroll")                                                          \
    for (int c = 0; c < CATS; ++c) {                                           \
        float sc = Oa.x * wc[c];                                               \
        sc = fmaf(Oa.y, wc[10 + c], sc);                                       \
        sc = fmaf(Oa.z, wc[20 + c], sc);                                       \
        sc = fmaf(Oa.w, wc[30 + c], sc);                                       \
        sc = fmaf(Ob.x, wc[40 + c], sc);                                       \
        sc = fmaf(Ob.y, wc[50 + c], sc);                                       \
        sc = fmaf(Ob.z, wc[60 + c], sc);                                       \
        sc = fmaf(Ob.w, wc[70 + c], sc);                                       \
        sc = wave_reduce_halves(sc);                                           \
        float slo = dpp_mov<0x143, 0xc>(sc);                                   \
        double d = (double)sc + (double)slo + biasd[c];                        \
        if (d > best) { best = d; bi = c; }                                    \
    }                                                                          \
    float sn = Ea.x * w[0];                                                    \
    sn = fmaf(Ea.y, w[1], sn);                                                 \
    sn = fmaf(Ea.z, w[2], sn);                                                 \
    sn = fmaf(Ea.w, w[3], sn);                                                 \
    sn = fmaf(Eb.x, w[4], sn);                                                 \
    sn = fmaf(Eb.y, w[5], sn);                                                 \
    sn = fmaf(Eb.z, w[6], sn);                                                 \
    sn = fmaf(Eb.w, w[7], sn);                                                 \
    sn = wave_reduce_full(sn);                                                 \
    if (lane == 63) {                                                          \
        float2 o2 = make_float2(tanhf(sn + bias), (float)bi);                  \
        *(float2*)(out + (size_t)r * NCOL + 2 * p) = o2;                       \
    }                                                                          \
    s = (s == 2) ? 0 : s + 1;                                                  \
    r += NBODY;                                                                \
} while (0)

// R12 structure: persistent 768 blocks (3/CU, no dispatch rounds), global
// moving-window traversal (stride 192), wave-private 3-slot global_load_lds
// ring with early refill. This round's single change: NT cache policy.
__global__ __launch_bounds__(256, 3) void pair_sweep_nt_kernel(
    const float* __restrict__ x,
    const float* __restrict__ Wn,
    const float* __restrict__ bn,
    const float* __restrict__ Wc,
    const float* __restrict__ bc,
    float* __restrict__ out)
{
    // wave-private 3-slot ring: 4 waves x 3 slots x 4 KiB = 48 KiB/block
    __shared__ __align__(16) float slab[4][3][1024];

    const int lane  = threadIdx.x & 63;
    const int wslot = threadIdx.x >> 6;
    const int q     = __builtin_amdgcn_readfirstlane(blockIdx.x & 3);  // quad
    const int body  = __builtin_amdgcn_readfirstlane(blockIdx.x >> 2); // 0..191
    const int p     = __builtin_amdgcn_readfirstlane(q * 4 + wslot);   // pair
    const size_t xcoloff = (size_t)p * (2 * DDIM);  // float offset of pair cols

    // ---- numeric weights (per-lane slice of Wn[p])
    float w[8];
    {
        float4 wa = *(const float4*)(Wn + p * DDIM + lane * 4);
        float4 wb = *(const float4*)(Wn + p * DDIM + 256 + lane * 4);
        w[0]=wa.x; w[1]=wa.y; w[2]=wa.z; w[3]=wa.w;
        w[4]=wb.x; w[5]=wb.y; w[6]=wb.z; w[7]=wb.w;
    }
    const float bias = __int_as_float(
        __builtin_amdgcn_readfirstlane(__float_as_int(bn[p])));

    // ---- categorical weights: wc[dd*10+c] low half, wc[40+dd*10+c] high half
    float wc[80];
    {
        const float* w0 = Wc + ((size_t)p * DDIM + lane * 4) * CATS;
        const float* w1 = Wc + ((size_t)p * DDIM + 256 + lane * 4) * CATS;
        #pragma unroll
        for (int k = 0; k < 10; ++k) {
            float4 t = *(const float4*)(w0 + k * 4);
            wc[4*k] = t.x; wc[4*k+1] = t.y; wc[4*k+2] = t.z; wc[4*k+3] = t.w;
        }
        #pragma unroll
        for (int k = 0; k < 10; ++k) {
            float4 t = *(const float4*)(w1 + k * 4);
            wc[40+4*k] = t.x; wc[40+4*k+1] = t.y; wc[40+4*k+2] = t.z; wc[40+4*k+3] = t.w;
        }
    }
    double biasd[CATS];  // wave-uniform -> SGPR pairs
    #pragma unroll
    for (int c = 0; c < CATS; ++c)
        biasd[c] = (double)__int_as_float(
            __builtin_amdgcn_readfirstlane(__float_as_int(bc[p * CATS + c])));

    // rows: body + 192*j, j = 0..n-1  (n = 43 for body<128 else 42)
    const int n = __builtin_amdgcn_readfirstlane(
        (TOTROWS - body + NBODY - 1) / NBODY);

    // ---- prologue: fill the 3 slots
    ISSUE(body,             0);
    ISSUE(body + NBODY,     1);
    ISSUE(body + 2 * NBODY, 2);

    int s = 0;
    int r = body;                      // row being processed
    int ri = body + 3 * NBODY;         // next row to issue
    // vmcnt accounting (stores count): ops newer than row r's last load are
    // at most {L_{r+1}(4), s_{r-2}(1), L_{r+2}(4), s_{r-1}(1)} = 10; waiting
    // to 8 always retires L_r (slightly conservative, never racy).
    for (int j = 0; j < n - 3; ++j) {
        STEP(WAITVM(8), { ISSUE(ri, s); ri += NBODY; });
    }
    // tails: no more issues; newer-than-L counts shrink to 9 -> 5 -> 1
    STEP(WAITVM(8), {});
    STEP(WAITVM(5), {});
    STEP(WAITVM(1), {});
}

extern "C" void kernel_launch(void* const* d_in, const int* in_sizes, int n_in,
                              void* d_out, int out_size, void* d_ws, size_t ws_size,
                              hipStream_t stream) {
    const float* x  = (const float*)d_in[0];
    const float* Wn = (const float*)d_in[1];
    const float* bn = (const float*)d_in[2];
    const float* Wc = (const float*)d_in[3];
    const float* bc = (const float*)d_in[4];
    float* out = (float*)d_out;

    // 768 blocks = 4 quads x 192 bodies; exactly 3 blocks/CU co-resident.
    hipLaunchKernelGGL(pair_sweep_nt_kernel, dim3(768), dim3(256), 0, stream,
                       x, Wn, bn, Wc, bc, out);
}